// Round 7
// baseline (284.586 us; speedup 1.0000x reference)
//
#include <hip/hip_runtime.h>
#include <hip/hip_bf16.h>

typedef _Float16 f16;
typedef _Float16 half4 __attribute__((ext_vector_type(4)));
typedef float floatx4 __attribute__((ext_vector_type(4)));

// Problem: B=8, C=256, H=W=64, sd=128, HEADS=8, hd=16, window L=256 tokens.
// idx0 = 64x4 column strips (wi = w>>2, t = h*4+(w&3)),
// idx1 = 4x64 row strips   (wi = h>>2, t = (h&3)*64+w).
// Layouts (f16), per idx:
//   qw,kw: token-major [winG(128)][t(256)][hc(128)]   (hc = head*16+d)
//   vw,lepe,ow: c-major [winG(128)][hc(128)][t(256)]
// WIN = elems per [idx] tensor = 4194304.
#define WIN 4194304

// ws (f16 elems): wqB 65536 | qw 2W | kw 2W | vw 2W | lep 2W | ow0 2W.
// ow2 aliases lep: attn reads lb[x] then writes ob[x] at identical element
// addresses, each element owned by exactly one lane -> race-free.

// ---- weight prep: wqB[part][kt][nt][lane][kj] (B-frag-ordered)
__global__ void k_prep(const float* __restrict__ wq, f16* __restrict__ wqB) {
    int D = blockIdx.x * 256 + threadIdx.x;
    if (D >= 49152) return;
    int kj = D & 3, lane = (D >> 2) & 63, nt = (D >> 8) & 7;
    int kt = (D >> 11) & 7, part = D >> 14;
    int g = lane >> 4, ln = lane & 15;
    int o = part * 128 + nt * 16 + ln;
    int k = kt * 16 + g * 4 + kj;
    wqB[D] = (f16)wq[o * 128 + k];
}

// ---- MFMA projection, pixel-row tiled: M=128 px (2 h-rows), K=128, N=384
// grid (32 row-pairs, 8 b, 2 idx) = 512 blocks, 256 threads (4 waves, M=32 each)
__global__ __launch_bounds__(256, 2) void k_proj(
    const float* __restrict__ x, const f16* __restrict__ wqB,
    f16* __restrict__ qw, f16* __restrict__ kw, f16* __restrict__ vw, int s)
{
    const int rt = blockIdx.x, b = blockIdx.y, idx = blockIdx.z;
    const int h0 = rt * 2;
    const int tid = threadIdx.x;
    const int wave = tid >> 6, lane = tid & 63, g = lane >> 4, ln = lane & 15;

    union __align__(16) SM {
        f16 xa[32 * 128 * 4];   // 32 KB  A chunked [kc(32)][m(128)][kj(4)]
        f16 pt[128 * 136];      // 34.8 KB transpose tile
    };
    __shared__ SM sm;

    // stage x -> f16 chunked LDS; full 256B rows of x, each element once
    for (int ii = tid; ii < 4096; ii += 256) {
        int c = ii >> 5, j = ii & 31;
        int row = j >> 4, w4 = (j & 15) << 2;
        int gc = (idx * 128 + c + s) & 255;
        int gh = (h0 + row + s) & 63;
        float4 v4 = *(const float4*)&x[(((size_t)b * 256 + gc) << 12) + (gh << 6) + w4];
        const float* vp = (const float*)&v4;
        int m0 = (row << 6) + w4;
        #pragma unroll
        for (int jj = 0; jj < 4; ++jj)
            sm.xa[((c >> 2) * 128 + m0 + jj) * 4 + (c & 3)] = (f16)vp[jj];
    }
    __syncthreads();

    // A-frags (held across parts): A[m=px][k=c]
    half4 af[2][8];
    #pragma unroll
    for (int mt = 0; mt < 2; ++mt)
        #pragma unroll
        for (int kt = 0; kt < 8; ++kt) {
            int m = wave * 32 + mt * 16 + ln;
            af[mt][kt] = *(const half4*)&sm.xa[((kt * 4 + g) * 128 + m) * 4];
        }

    for (int part = 0; part < 3; ++part) {
        floatx4 C[8][2];
        #pragma unroll
        for (int nt = 0; nt < 8; ++nt)
            #pragma unroll
            for (int mt = 0; mt < 2; ++mt) C[nt][mt] = (floatx4){0.f, 0.f, 0.f, 0.f};

        for (int kt = 0; kt < 8; ++kt) {
            half4 bf[8];
            #pragma unroll
            for (int nt = 0; nt < 8; ++nt)
                bf[nt] = *(const half4*)&wqB[((((part * 8 + kt) * 8 + nt) * 64) + lane) * 4];
            #pragma unroll
            for (int nt = 0; nt < 8; ++nt)
                #pragma unroll
                for (int mt = 0; mt < 2; ++mt)
                    C[nt][mt] = __builtin_amdgcn_mfma_f32_16x16x16f16(
                        af[mt][kt], bf[nt], C[nt][mt], 0, 0, 0);
        }

        // q: fold softmax scale AND log2(e) (attn uses exp2)
        const float qsc = (part == 0) ? 0.25f * 1.4426950408889634f : 1.0f;

        __syncthreads();    // xa (part0) / previous pt reads done
        #pragma unroll
        for (int nt = 0; nt < 8; ++nt)
            #pragma unroll
            for (int mt = 0; mt < 2; ++mt)
                #pragma unroll
                for (int r = 0; r < 4; ++r) {
                    int m = wave * 32 + mt * 16 + g * 4 + r;
                    int c = nt * 16 + ln;                 // part-local o
                    int hc = ((c & 7) << 4) + (c >> 3);   // head*16+d
                    f16 hv = (f16)(C[nt][mt][r] * qsc);
                    if (part == 2) sm.pt[hc * 136 + m] = hv;   // v: [hc][m]
                    else           sm.pt[m * 136 + hc] = hv;   // q/k: [m][hc]
                }
        __syncthreads();

        if (part < 2) {
            // token-major store: [winG][t][hc], 256B-contiguous per m
            f16* dst = (part == 0 ? qw : kw) + (size_t)idx * WIN;
            int tq = tid >> 4, hcg = tid & 15;
            #pragma unroll
            for (int it = 0; it < 8; ++it) {
                int m = it * 16 + tq;
                int h = h0 + (m >> 6), w = m & 63;
                int winG, t;
                if (idx == 0) { winG = b * 16 + (w >> 2); t = (h << 2) | (w & 3); }
                else          { winG = b * 16 + (h >> 2); t = ((h & 3) << 6) | w; }
                *(float4*)(dst + (((size_t)winG * 256 + t) << 7) + hcg * 8) =
                    *(const float4*)&sm.pt[m * 136 + hcg * 8];
            }
        } else {
            // c-major store: [winG][hc][t]
            f16* dst = vw + (size_t)idx * WIN;
            int mg = tid & 15, hcq = tid >> 4;
            int row = mg >> 3, h = h0 + row;
            #pragma unroll
            for (int it = 0; it < 8; ++it) {
                int hc = it * 16 + hcq;
                if (idx == 1) {
                    int w = (mg & 7) * 8;
                    int winG = b * 16 + (h >> 2);
                    int t = ((h & 3) << 6) | w;
                    *(float4*)(dst + (((size_t)winG * 128 + hc) << 8) + t) =
                        *(const float4*)&sm.pt[hc * 136 + mg * 8];
                } else {
                    #pragma unroll
                    for (int q2 = 0; q2 < 2; ++q2) {
                        int w0 = (mg & 7) * 8 + q2 * 4;
                        int winG = b * 16 + (w0 >> 2);
                        int t = h << 2;   // +0..3 via the 4 consecutive elems
                        *(half4*)(dst + (((size_t)winG * 128 + hc) << 8) + t) =
                            *(const half4*)&sm.pt[hc * 136 + mg * 8 + q2 * 4];
                    }
                }
            }
        }
    }
}

// ---- LePE dwconv3x3 in window domain, LDS halo staging
// grid (128 winG, 2 idx, 16 hc-slices of 8), 256 threads = t
__global__ __launch_bounds__(256) void k_lepe(
    const f16* __restrict__ vw, const float* __restrict__ wle,
    const float* __restrict__ ble, f16* __restrict__ lepe)
{
    const int winG = blockIdx.x, idx = blockIdx.y, hg = blockIdx.z;
    const int wi = winG & 15;
    const int tid = threadIdx.x;
    const int hc0 = hg * 8;
    const f16* vb = vw + (size_t)idx * WIN;
    f16* lb = lepe + (size_t)idx * WIN;

    __shared__ f16 sp[4096];

    if (idx == 0) {
        // view [hcl(8)][h(64)][wp(8)]: wp=0 left halo, 1..4 center, 5 right halo
        for (int ii = tid; ii < 8 * 256; ii += 256) {
            int hcl = ii >> 8, t = ii & 255;
            f16 v = vb[(((size_t)winG * 128 + hc0 + hcl) << 8) + t];
            sp[(hcl << 9) + ((t >> 2) << 3) + 1 + (t & 3)] = v;
        }
        for (int ii = tid; ii < 8 * 128; ii += 256) {
            int hcl = ii >> 7, j = ii & 127;
            int side = j >> 6, h = j & 63;
            f16 v = (f16)0.f;
            if (side == 0) { if (wi > 0)
                v = vb[(((size_t)(winG - 1) * 128 + hc0 + hcl) << 8) + h * 4 + 3]; }
            else           { if (wi < 15)
                v = vb[(((size_t)(winG + 1) * 128 + hc0 + hcl) << 8) + h * 4]; }
            sp[(hcl << 9) + (h << 3) + (side ? 5 : 0)] = v;
        }
        __syncthreads();
        int h = tid >> 2, wp = 1 + (tid & 3);
        for (int hcl = 0; hcl < 8; ++hcl) {
            int hc = hc0 + hcl, d = hc & 15, head = hc >> 4;
            int c = d * 8 + head;
            float acc = ble[c];
            #pragma unroll
            for (int ky = 0; ky < 3; ++ky) {
                int hh = h + ky - 1;
                if (hh < 0 || hh > 63) continue;
                #pragma unroll
                for (int kx = 0; kx < 3; ++kx)
                    acc = fmaf(wle[c * 9 + ky * 3 + kx],
                               (float)sp[(hcl << 9) + (hh << 3) + wp + kx - 1], acc);
            }
            lb[(((size_t)winG * 128 + hc) << 8) + tid] = (f16)acc;
        }
    } else {
        // view [hcl(8)][hp(6)][68]: hp=0 top halo, 1..4 center, 5 bottom halo
        const int ROW = 68;
        for (int ii = tid; ii < 8 * 256; ii += 256) {
            int hcl = ii >> 8, t = ii & 255;
            f16 v = vb[(((size_t)winG * 128 + hc0 + hcl) << 8) + t];
            sp[hcl * 6 * ROW + (1 + (t >> 6)) * ROW + 1 + (t & 63)] = v;
        }
        for (int ii = tid; ii < 8 * 128; ii += 256) {
            int hcl = ii >> 7, j = ii & 127;
            int side = j >> 6, w = j & 63;
            f16 v = (f16)0.f;
            if (side == 0) { if (wi > 0)
                v = vb[(((size_t)(winG - 1) * 128 + hc0 + hcl) << 8) + 192 + w]; }
            else           { if (wi < 15)
                v = vb[(((size_t)(winG + 1) * 128 + hc0 + hcl) << 8) + w]; }
            sp[hcl * 6 * ROW + (side ? 5 : 0) * ROW + 1 + w] = v;
        }
        for (int ii = tid; ii < 8 * 6 * 2; ii += 256) {
            int hcl = ii / 12, rr = (ii % 12) >> 1, e = ii & 1;
            sp[hcl * 6 * ROW + rr * ROW + (e ? 65 : 0)] = (f16)0.f;
        }
        __syncthreads();
        int hloc = tid >> 6, w = tid & 63;
        for (int hcl = 0; hcl < 8; ++hcl) {
            int hc = hc0 + hcl, d = hc & 15, head = hc >> 4;
            int c = d * 8 + head;
            float acc = ble[c];
            #pragma unroll
            for (int ky = 0; ky < 3; ++ky)
                #pragma unroll
                for (int kx = 0; kx < 3; ++kx)
                    acc = fmaf(wle[c * 9 + ky * 3 + kx],
                               (float)sp[hcl * 6 * ROW + (hloc + ky) * ROW + w + kx],
                               acc);
            lb[(((size_t)winG * 128 + hc) << 8) + tid] = (f16)acc;
        }
    }
}

// ---- MFMA attention + LePE add, writes ow (c-major f16)
// 2048 blocks x 256 threads; wave = (winG, idx, head, q-quarter of 64)
__global__ __launch_bounds__(256) void k_attn(
    const f16* __restrict__ qw, const f16* __restrict__ kw,
    const f16* __restrict__ vw, const f16* __restrict__ lep,
    f16* __restrict__ ow)
{
    const int lane = threadIdx.x & 63;
    const int g = lane >> 4, ln = lane & 15;
    const int W = blockIdx.x * 4 + (threadIdx.x >> 6);
    const int qquad = W & 3, head = (W >> 2) & 7, idx = (W >> 5) & 1, winG = W >> 6;

    const size_t cb = ((size_t)(winG * 8 + head)) << 4;   // c-major: (+d)<<8 + t
    const f16* qb = qw + (size_t)idx * WIN + ((size_t)winG << 15) + head * 16;
    const f16* kb = kw + (size_t)idx * WIN + ((size_t)winG << 15) + head * 16;
    const f16* vb = vw + (size_t)idx * WIN;
    const f16* lb = lep + (size_t)idx * WIN;
    f16* ob = ow + (size_t)idx * WIN;

    // Q^T B-frags: B[k=d=g*4+j][n=query=ln]  (token-major: half4)
    half4 qf[4];
    #pragma unroll
    for (int qt = 0; qt < 4; ++qt) {
        int t = qquad * 64 + qt * 16 + ln;
        qf[qt] = *(const half4*)(qb + ((size_t)t << 7) + g * 4);
    }

    floatx4 o[4]; float lsum[4];
    #pragma unroll
    for (int qt = 0; qt < 4; ++qt) { o[qt] = (floatx4){0.f,0.f,0.f,0.f}; lsum[qt] = 0.f; }

    for (int kt = 0; kt < 16; ++kt) {
        // K A-frag: A[m=key=ln][k=d]  (token-major: half4)
        half4 kf = *(const half4*)(kb + ((size_t)(kt * 16 + ln) << 7) + g * 4);
        // V^T A-frag: A[m=d=ln][k=key] (c-major: half4)
        half4 vf = *(const half4*)&vb[((cb + ln) << 8) + kt * 16 + g * 4];
        #pragma unroll
        for (int qt = 0; qt < 4; ++qt) {
            floatx4 sc = __builtin_amdgcn_mfma_f32_16x16x16f16(
                kf, qf[qt], (floatx4){0.f,0.f,0.f,0.f}, 0, 0, 0);
            // q pre-scaled by 0.25*log2(e): exp(s) = exp2(sc)
            float p0 = __builtin_amdgcn_exp2f(sc[0]);
            float p1 = __builtin_amdgcn_exp2f(sc[1]);
            float p2 = __builtin_amdgcn_exp2f(sc[2]);
            float p3 = __builtin_amdgcn_exp2f(sc[3]);
            lsum[qt] += (p0 + p1) + (p2 + p3);
            half4 pf = {(f16)p0, (f16)p1, (f16)p2, (f16)p3};
            o[qt] = __builtin_amdgcn_mfma_f32_16x16x16f16(vf, pf, o[qt], 0, 0, 0);
        }
    }

    #pragma unroll
    for (int qt = 0; qt < 4; ++qt) {
        float l = lsum[qt];
        l += __shfl_xor(l, 16);
        l += __shfl_xor(l, 32);
        float inv = 1.f / l;
        int t = qquad * 64 + qt * 16 + ln;
        #pragma unroll
        for (int r = 0; r < 4; ++r) {
            int d = g * 4 + r;
            float val = fmaf(o[qt][r], inv, (float)lb[((cb + d) << 8) + t]);
            ob[((cb + d) << 8) + t] = (f16)val;
        }
    }
}

// ---- combine shifts + inverse roll, single coalesced out write
__global__ __launch_bounds__(256) void k_final(
    const f16* __restrict__ ow0, const f16* __restrict__ ow2,
    float* __restrict__ out)
{
    #pragma unroll
    for (int it = 0; it < 4; ++it) {
        int e = blockIdx.x * 1024 + it * 256 + threadIdx.x;
        int w = e & 63, oh = (e >> 6) & 63, oc = (e >> 12) & 255, b = e >> 20;
        float acc = 0.f;
        #pragma unroll
        for (int si = 0; si < 2; ++si) {
            int s = si * 2;
            const f16* p = si ? ow2 : ow0;
            int idx = oc >> 7;
            int cl = ((oc & 127) - s) & 127;
            int h = (oh - s) & 63;
            int head = cl & 7, d = cl >> 3;
            int wg, t;
            if (idx == 0) { wg = b * 16 + (w >> 2); t = (h << 2) | (w & 3); }
            else          { wg = b * 16 + (h >> 2); t = ((h & 3) << 6) | w; }
            acc += (float)p[(size_t)idx * WIN
                            + (((size_t)(wg * 8 + head) * 16 + d) << 8) + t];
        }
        out[e] = acc;
    }
}

extern "C" void kernel_launch(void* const* d_in, const int* in_sizes, int n_in,
                              void* d_out, int out_size, void* d_ws, size_t ws_size,
                              hipStream_t stream) {
    const float* x      = (const float*)d_in[0];
    const float* w_qkv  = (const float*)d_in[1];
    const float* w_lepe = (const float*)d_in[2];
    const float* b_lepe = (const float*)d_in[3];
    float* out = (float*)d_out;

    f16* wsf = (f16*)d_ws;
    f16* wqB = wsf;                         // 49152 used, 65536 reserved
    f16* qw  = wsf + 65536;
    f16* kw  = qw + 2 * (size_t)WIN;
    f16* vw  = kw + 2 * (size_t)WIN;
    f16* lep = vw + 2 * (size_t)WIN;
    f16* ow0 = lep + 2 * (size_t)WIN;
    f16* ow2 = lep;                         // alias (see header comment)

    k_prep<<<192, 256, 0, stream>>>(w_qkv, wqB);

    k_proj<<<dim3(32, 8, 2), 256, 0, stream>>>(x, wqB, qw, kw, vw, 0);
    k_lepe<<<dim3(128, 2, 16), 256, 0, stream>>>(vw, w_lepe, b_lepe, lep);
    k_attn<<<2048, 256, 0, stream>>>(qw, kw, vw, lep, ow0);

    k_proj<<<dim3(32, 8, 2), 256, 0, stream>>>(x, wqB, qw, kw, vw, 2);
    k_lepe<<<dim3(128, 2, 16), 256, 0, stream>>>(vw, w_lepe, b_lepe, lep);
    k_attn<<<2048, 256, 0, stream>>>(qw, kw, vw, lep, ow2);

    k_final<<<8192, 256, 0, stream>>>(ow0, ow2, out);
}

// Round 8
// 259.178 us; speedup vs baseline: 1.0980x; 1.0980x over previous
//
#include <hip/hip_runtime.h>
#include <hip/hip_bf16.h>

typedef _Float16 f16;
typedef _Float16 half4 __attribute__((ext_vector_type(4)));
typedef float floatx4 __attribute__((ext_vector_type(4)));

// Problem: B=8, C=256, H=W=64, sd=128, HEADS=8, hd=16, window L=256 tokens.
// idx0 = 64x4 column strips (wi = w>>2, t = h*4+(w&3)),
// idx1 = 4x64 row strips   (wi = h>>2, t = (h&3)*64+w).
// Layouts (f16), per idx:
//   qw,kw: token-major [winG(128)][t(256)][hc(128)]   (hc = head*16+d)
//   vw,lepe,ow: c-major [winG(128)][hc(128)][t(256)]
// WIN = elems per [idx] tensor = 4194304.
#define WIN 4194304

// ws (f16 elems): wqB 65536 | qw 2W | kw 2W | vw 2W | lep 2W | ow0 2W.
// ow2 aliases lep: attn reads lb[x] then writes ob[x] at identical element
// addresses, each element owned by exactly one lane -> race-free.

// ---- weight prep: wqB[part][kt][nt][lane][kj] (B-frag-ordered)
__global__ void k_prep(const float* __restrict__ wq, f16* __restrict__ wqB) {
    int D = blockIdx.x * 256 + threadIdx.x;
    if (D >= 49152) return;
    int kj = D & 3, lane = (D >> 2) & 63, nt = (D >> 8) & 7;
    int kt = (D >> 11) & 7, part = D >> 14;
    int g = lane >> 4, ln = lane & 15;
    int o = part * 128 + nt * 16 + ln;
    int k = kt * 16 + g * 4 + kj;
    wqB[D] = (f16)wq[o * 128 + k];
}

// ---- MFMA projection, pixel-row tiled: M=128 px (2 h-rows), K=128, N=384
// grid (32 row-pairs, 8 b, 2 idx) = 512 blocks, 256 threads (4 waves, M=32 each)
__global__ __launch_bounds__(256, 2) void k_proj(
    const float* __restrict__ x, const f16* __restrict__ wqB,
    f16* __restrict__ qw, f16* __restrict__ kw, f16* __restrict__ vw, int s)
{
    const int rt = blockIdx.x, b = blockIdx.y, idx = blockIdx.z;
    const int h0 = rt * 2;
    const int tid = threadIdx.x;
    const int wave = tid >> 6, lane = tid & 63, g = lane >> 4, ln = lane & 15;

    union __align__(16) SM {
        f16 xa[32 * 128 * 4];   // 32 KB  A chunked [kc(32)][m(128)][kj(4)]
        f16 pt[128 * 136];      // 34.8 KB transpose tile
    };
    __shared__ SM sm;

    // stage x -> f16 chunked LDS; full 256B rows of x, each element once
    for (int ii = tid; ii < 4096; ii += 256) {
        int c = ii >> 5, j = ii & 31;
        int row = j >> 4, w4 = (j & 15) << 2;
        int gc = (idx * 128 + c + s) & 255;
        int gh = (h0 + row + s) & 63;
        float4 v4 = *(const float4*)&x[(((size_t)b * 256 + gc) << 12) + (gh << 6) + w4];
        const float* vp = (const float*)&v4;
        int m0 = (row << 6) + w4;
        #pragma unroll
        for (int jj = 0; jj < 4; ++jj)
            sm.xa[((c >> 2) * 128 + m0 + jj) * 4 + (c & 3)] = (f16)vp[jj];
    }
    __syncthreads();

    // A-frags (held across parts): A[m=px][k=c]
    half4 af[2][8];
    #pragma unroll
    for (int mt = 0; mt < 2; ++mt)
        #pragma unroll
        for (int kt = 0; kt < 8; ++kt) {
            int m = wave * 32 + mt * 16 + ln;
            af[mt][kt] = *(const half4*)&sm.xa[((kt * 4 + g) * 128 + m) * 4];
        }

    for (int part = 0; part < 3; ++part) {
        floatx4 C[8][2];
        #pragma unroll
        for (int nt = 0; nt < 8; ++nt)
            #pragma unroll
            for (int mt = 0; mt < 2; ++mt) C[nt][mt] = (floatx4){0.f, 0.f, 0.f, 0.f};

        for (int kt = 0; kt < 8; ++kt) {
            half4 bf[8];
            #pragma unroll
            for (int nt = 0; nt < 8; ++nt)
                bf[nt] = *(const half4*)&wqB[((((part * 8 + kt) * 8 + nt) * 64) + lane) * 4];
            #pragma unroll
            for (int nt = 0; nt < 8; ++nt)
                #pragma unroll
                for (int mt = 0; mt < 2; ++mt)
                    C[nt][mt] = __builtin_amdgcn_mfma_f32_16x16x16f16(
                        af[mt][kt], bf[nt], C[nt][mt], 0, 0, 0);
        }

        // q: fold softmax scale AND log2(e) (attn uses exp2)
        const float qsc = (part == 0) ? 0.25f * 1.4426950408889634f : 1.0f;

        __syncthreads();    // xa (part0) / previous pt reads done
        #pragma unroll
        for (int nt = 0; nt < 8; ++nt)
            #pragma unroll
            for (int mt = 0; mt < 2; ++mt)
                #pragma unroll
                for (int r = 0; r < 4; ++r) {
                    int m = wave * 32 + mt * 16 + g * 4 + r;
                    int c = nt * 16 + ln;                 // part-local o
                    int hc = ((c & 7) << 4) + (c >> 3);   // head*16+d
                    f16 hv = (f16)(C[nt][mt][r] * qsc);
                    if (part == 2) sm.pt[hc * 136 + m] = hv;   // v: [hc][m]
                    else           sm.pt[m * 136 + hc] = hv;   // q/k: [m][hc]
                }
        __syncthreads();

        if (part < 2) {
            // token-major store: [winG][t][hc], 256B-contiguous per m
            f16* dst = (part == 0 ? qw : kw) + (size_t)idx * WIN;
            int tq = tid >> 4, hcg = tid & 15;
            #pragma unroll
            for (int it = 0; it < 8; ++it) {
                int m = it * 16 + tq;
                int h = h0 + (m >> 6), w = m & 63;
                int winG, t;
                if (idx == 0) { winG = b * 16 + (w >> 2); t = (h << 2) | (w & 3); }
                else          { winG = b * 16 + (h >> 2); t = ((h & 3) << 6) | w; }
                *(float4*)(dst + (((size_t)winG * 256 + t) << 7) + hcg * 8) =
                    *(const float4*)&sm.pt[m * 136 + hcg * 8];
            }
        } else {
            // c-major store: [winG][hc][t]
            f16* dst = vw + (size_t)idx * WIN;
            int mg = tid & 15, hcq = tid >> 4;
            int row = mg >> 3, h = h0 + row;
            #pragma unroll
            for (int it = 0; it < 8; ++it) {
                int hc = it * 16 + hcq;
                if (idx == 1) {
                    int w = (mg & 7) * 8;
                    int winG = b * 16 + (h >> 2);
                    int t = ((h & 3) << 6) | w;
                    *(float4*)(dst + (((size_t)winG * 128 + hc) << 8) + t) =
                        *(const float4*)&sm.pt[hc * 136 + mg * 8];
                } else {
                    #pragma unroll
                    for (int q2 = 0; q2 < 2; ++q2) {
                        int w0 = (mg & 7) * 8 + q2 * 4;
                        int winG = b * 16 + (w0 >> 2);
                        int t = h << 2;   // +0..3 via the 4 consecutive elems
                        *(half4*)(dst + (((size_t)winG * 128 + hc) << 8) + t) =
                            *(const half4*)&sm.pt[hc * 136 + mg * 8 + q2 * 4];
                    }
                }
            }
        }
    }
}

// ---- LePE dwconv3x3 in window domain, LDS halo staging
// grid (128 winG, 2 idx, 16 hc-slices of 8), 256 threads = t
__global__ __launch_bounds__(256) void k_lepe(
    const f16* __restrict__ vw, const float* __restrict__ wle,
    const float* __restrict__ ble, f16* __restrict__ lepe)
{
    const int winG = blockIdx.x, idx = blockIdx.y, hg = blockIdx.z;
    const int wi = winG & 15;
    const int tid = threadIdx.x;
    const int hc0 = hg * 8;
    const f16* vb = vw + (size_t)idx * WIN;
    f16* lb = lepe + (size_t)idx * WIN;

    __shared__ f16 sp[4096];

    if (idx == 0) {
        // view [hcl(8)][h(64)][wp(8)]: wp=0 left halo, 1..4 center, 5 right halo
        for (int ii = tid; ii < 8 * 256; ii += 256) {
            int hcl = ii >> 8, t = ii & 255;
            f16 v = vb[(((size_t)winG * 128 + hc0 + hcl) << 8) + t];
            sp[(hcl << 9) + ((t >> 2) << 3) + 1 + (t & 3)] = v;
        }
        for (int ii = tid; ii < 8 * 128; ii += 256) {
            int hcl = ii >> 7, j = ii & 127;
            int side = j >> 6, h = j & 63;
            f16 v = (f16)0.f;
            if (side == 0) { if (wi > 0)
                v = vb[(((size_t)(winG - 1) * 128 + hc0 + hcl) << 8) + h * 4 + 3]; }
            else           { if (wi < 15)
                v = vb[(((size_t)(winG + 1) * 128 + hc0 + hcl) << 8) + h * 4]; }
            sp[(hcl << 9) + (h << 3) + (side ? 5 : 0)] = v;
        }
        __syncthreads();
        int h = tid >> 2, wp = 1 + (tid & 3);
        for (int hcl = 0; hcl < 8; ++hcl) {
            int hc = hc0 + hcl, d = hc & 15, head = hc >> 4;
            int c = d * 8 + head;
            float acc = ble[c];
            #pragma unroll
            for (int ky = 0; ky < 3; ++ky) {
                int hh = h + ky - 1;
                if (hh < 0 || hh > 63) continue;
                #pragma unroll
                for (int kx = 0; kx < 3; ++kx)
                    acc = fmaf(wle[c * 9 + ky * 3 + kx],
                               (float)sp[(hcl << 9) + (hh << 3) + wp + kx - 1], acc);
            }
            lb[(((size_t)winG * 128 + hc) << 8) + tid] = (f16)acc;
        }
    } else {
        // view [hcl(8)][hp(6)][68]: hp=0 top halo, 1..4 center, 5 bottom halo
        const int ROW = 68;
        for (int ii = tid; ii < 8 * 256; ii += 256) {
            int hcl = ii >> 8, t = ii & 255;
            f16 v = vb[(((size_t)winG * 128 + hc0 + hcl) << 8) + t];
            sp[hcl * 6 * ROW + (1 + (t >> 6)) * ROW + 1 + (t & 63)] = v;
        }
        for (int ii = tid; ii < 8 * 128; ii += 256) {
            int hcl = ii >> 7, j = ii & 127;
            int side = j >> 6, w = j & 63;
            f16 v = (f16)0.f;
            if (side == 0) { if (wi > 0)
                v = vb[(((size_t)(winG - 1) * 128 + hc0 + hcl) << 8) + 192 + w]; }
            else           { if (wi < 15)
                v = vb[(((size_t)(winG + 1) * 128 + hc0 + hcl) << 8) + w]; }
            sp[hcl * 6 * ROW + (side ? 5 : 0) * ROW + 1 + w] = v;
        }
        for (int ii = tid; ii < 8 * 6 * 2; ii += 256) {
            int hcl = ii / 12, rr = (ii % 12) >> 1, e = ii & 1;
            sp[hcl * 6 * ROW + rr * ROW + (e ? 65 : 0)] = (f16)0.f;
        }
        __syncthreads();
        int hloc = tid >> 6, w = tid & 63;
        for (int hcl = 0; hcl < 8; ++hcl) {
            int hc = hc0 + hcl, d = hc & 15, head = hc >> 4;
            int c = d * 8 + head;
            float acc = ble[c];
            #pragma unroll
            for (int ky = 0; ky < 3; ++ky)
                #pragma unroll
                for (int kx = 0; kx < 3; ++kx)
                    acc = fmaf(wle[c * 9 + ky * 3 + kx],
                               (float)sp[hcl * 6 * ROW + (hloc + ky) * ROW + w + kx],
                               acc);
            lb[(((size_t)winG * 128 + hc) << 8) + tid] = (f16)acc;
        }
    }
}

// ---- MFMA attention + LePE add, K/V staged in LDS (read once per block)
// grid 2048 blocks = (winG, idx, head); 256 threads; wave = q-quarter (64 q)
__global__ __launch_bounds__(256) void k_attn(
    const f16* __restrict__ qw, const f16* __restrict__ kw,
    const f16* __restrict__ vw, const f16* __restrict__ lep,
    f16* __restrict__ ow)
{
    const int tid = threadIdx.x;
    const int lane = tid & 63, wave = tid >> 6;
    const int g = lane >> 4, ln = lane & 15;
    const int head = blockIdx.x & 7, idx = (blockIdx.x >> 3) & 1;
    const int winG = blockIdx.x >> 4;

    __shared__ f16 kl[4096];   // frag-ordered [kt(16)][lane(64)][4]
    __shared__ f16 vl[4096];   // frag-ordered [kt(16)][lane(64)][4]

    const size_t cb = ((size_t)(winG * 8 + head)) << 4;   // c-major: (+d)<<8 + t
    const f16* qb = qw + (size_t)idx * WIN + ((size_t)winG << 15) + head * 16;
    const f16* kb = kw + (size_t)idx * WIN + ((size_t)winG << 15) + head * 16;
    const f16* vb = vw + (size_t)idx * WIN;
    const f16* lb = lep + (size_t)idx * WIN;
    f16* ob = ow + (size_t)idx * WIN;

    // stage K: thread = token t; K A-frag elem = k[t=kt*16+ln][d=g*4+j]
    {
        int t = tid;
        const f16* src = kb + ((size_t)t << 7);
        float4 a = *(const float4*)src;          // d0..7
        float4 b2 = *(const float4*)(src + 8);   // d8..15
        const f16* ap = (const f16*)&a;
        const f16* bp = (const f16*)&b2;
        int kt = t >> 4, l2 = t & 15;
        *(half4*)&kl[(kt * 64 + 0 * 16 + l2) * 4] = *(const half4*)(ap);
        *(half4*)&kl[(kt * 64 + 1 * 16 + l2) * 4] = *(const half4*)(ap + 4);
        *(half4*)&kl[(kt * 64 + 2 * 16 + l2) * 4] = *(const half4*)(bp);
        *(half4*)&kl[(kt * 64 + 3 * 16 + l2) * 4] = *(const half4*)(bp + 4);
    }
    // stage V (8KB contiguous): V^T A-frag elem = v[d=ln][t=kt*16+g*4+j]
    {
        const f16* src = vb + (cb << 8);
        #pragma unroll
        for (int r2 = 0; r2 < 2; ++r2) {
            int e = r2 * 256 + tid;              // float4 index 0..511
            float4 a = *(const float4*)(src + e * 8);
            const f16* ap = (const f16*)&a;
            int d = e >> 5;                      // 32 float4 per d-row
            int t0 = (e & 31) * 8;
            int kt0 = t0 >> 4, g0 = (t0 >> 2) & 3;
            *(half4*)&vl[(kt0 * 64 + g0 * 16 + d) * 4] = *(const half4*)ap;
            int t1 = t0 + 4;
            int kt1 = t1 >> 4, g1 = (t1 >> 2) & 3;
            *(half4*)&vl[(kt1 * 64 + g1 * 16 + d) * 4] = *(const half4*)(ap + 4);
        }
    }

    // Q^T B-frags: B[k=d=g*4+j][n=query=ln]  (token-major: half4)
    half4 qf[4];
    #pragma unroll
    for (int qt = 0; qt < 4; ++qt) {
        int t = wave * 64 + qt * 16 + ln;
        qf[qt] = *(const half4*)(qb + ((size_t)t << 7) + g * 4);
    }

    __syncthreads();

    floatx4 o[4]; float lsum[4];
    #pragma unroll
    for (int qt = 0; qt < 4; ++qt) { o[qt] = (floatx4){0.f,0.f,0.f,0.f}; lsum[qt] = 0.f; }

    for (int kt = 0; kt < 16; ++kt) {
        half4 kf = *(const half4*)&kl[(kt * 64 + lane) * 4];
        half4 vf = *(const half4*)&vl[(kt * 64 + lane) * 4];
        #pragma unroll
        for (int qt = 0; qt < 4; ++qt) {
            floatx4 sc = __builtin_amdgcn_mfma_f32_16x16x16f16(
                kf, qf[qt], (floatx4){0.f,0.f,0.f,0.f}, 0, 0, 0);
            // q pre-scaled by 0.25*log2(e): exp(s) = exp2(sc)
            float p0 = __builtin_amdgcn_exp2f(sc[0]);
            float p1 = __builtin_amdgcn_exp2f(sc[1]);
            float p2 = __builtin_amdgcn_exp2f(sc[2]);
            float p3 = __builtin_amdgcn_exp2f(sc[3]);
            lsum[qt] += (p0 + p1) + (p2 + p3);
            half4 pf = {(f16)p0, (f16)p1, (f16)p2, (f16)p3};
            o[qt] = __builtin_amdgcn_mfma_f32_16x16x16f16(vf, pf, o[qt], 0, 0, 0);
        }
    }

    #pragma unroll
    for (int qt = 0; qt < 4; ++qt) {
        float l = lsum[qt];
        l += __shfl_xor(l, 16);
        l += __shfl_xor(l, 32);
        float inv = 1.f / l;
        int t = wave * 64 + qt * 16 + ln;
        #pragma unroll
        for (int r = 0; r < 4; ++r) {
            int d = g * 4 + r;
            float val = fmaf(o[qt][r], inv, (float)lb[((cb + d) << 8) + t]);
            ob[((cb + d) << 8) + t] = (f16)val;
        }
    }
}

// ---- combine shifts + inverse roll, single coalesced out write
__global__ __launch_bounds__(256) void k_final(
    const f16* __restrict__ ow0, const f16* __restrict__ ow2,
    float* __restrict__ out)
{
    #pragma unroll
    for (int it = 0; it < 4; ++it) {
        int e = blockIdx.x * 1024 + it * 256 + threadIdx.x;
        int w = e & 63, oh = (e >> 6) & 63, oc = (e >> 12) & 255, b = e >> 20;
        float acc = 0.f;
        #pragma unroll
        for (int si = 0; si < 2; ++si) {
            int s = si * 2;
            const f16* p = si ? ow2 : ow0;
            int idx = oc >> 7;
            int cl = ((oc & 127) - s) & 127;
            int h = (oh - s) & 63;
            int head = cl & 7, d = cl >> 3;
            int wg, t;
            if (idx == 0) { wg = b * 16 + (w >> 2); t = (h << 2) | (w & 3); }
            else          { wg = b * 16 + (h >> 2); t = ((h & 3) << 6) | w; }
            acc += (float)p[(size_t)idx * WIN
                            + (((size_t)(wg * 8 + head) * 16 + d) << 8) + t];
        }
        out[e] = acc;
    }
}

extern "C" void kernel_launch(void* const* d_in, const int* in_sizes, int n_in,
                              void* d_out, int out_size, void* d_ws, size_t ws_size,
                              hipStream_t stream) {
    const float* x      = (const float*)d_in[0];
    const float* w_qkv  = (const float*)d_in[1];
    const float* w_lepe = (const float*)d_in[2];
    const float* b_lepe = (const float*)d_in[3];
    float* out = (float*)d_out;

    f16* wsf = (f16*)d_ws;
    f16* wqB = wsf;                         // 49152 used, 65536 reserved
    f16* qw  = wsf + 65536;
    f16* kw  = qw + 2 * (size_t)WIN;
    f16* vw  = kw + 2 * (size_t)WIN;
    f16* lep = vw + 2 * (size_t)WIN;
    f16* ow0 = lep + 2 * (size_t)WIN;
    f16* ow2 = lep;                         // alias (see header comment)

    k_prep<<<192, 256, 0, stream>>>(w_qkv, wqB);

    k_proj<<<dim3(32, 8, 2), 256, 0, stream>>>(x, wqB, qw, kw, vw, 0);
    k_lepe<<<dim3(128, 2, 16), 256, 0, stream>>>(vw, w_lepe, b_lepe, lep);
    k_attn<<<2048, 256, 0, stream>>>(qw, kw, vw, lep, ow0);

    k_proj<<<dim3(32, 8, 2), 256, 0, stream>>>(x, wqB, qw, kw, vw, 2);
    k_lepe<<<dim3(128, 2, 16), 256, 0, stream>>>(vw, w_lepe, b_lepe, lep);
    k_attn<<<2048, 256, 0, stream>>>(qw, kw, vw, lep, ow2);

    k_final<<<8192, 256, 0, stream>>>(ow0, ow2, out);
}